// Round 2
// baseline (503.170 us; speedup 1.0000x reference)
//
#include <hip/hip_runtime.h>
#include <cstdint>

typedef __attribute__((ext_vector_type(8))) short short8;
typedef __attribute__((ext_vector_type(4))) float f32x4;

static __device__ __forceinline__ unsigned short f2bf(float f) {
  unsigned int u = __float_as_uint(f);
  unsigned int r = (u + 0x7FFFu + ((u >> 16) & 1u)) >> 16;   // RNE
  return (unsigned short)r;
}
static __device__ __forceinline__ unsigned int pack2bf(float a, float b) {
  return (unsigned int)f2bf(a) | ((unsigned int)f2bf(b) << 16);
}
static __device__ __forceinline__ float2 bf2f(unsigned int u) {
  return make_float2(__uint_as_float(u << 16), __uint_as_float(u & 0xFFFF0000u));
}
static __device__ __forceinline__ void acc8(float* a, uint4 h, uint4 r) {
  float2 f, g;
  f = bf2f(h.x); g = bf2f(r.x); a[0] += f.x - g.x; a[1] += f.y - g.y;
  f = bf2f(h.y); g = bf2f(r.y); a[2] += f.x - g.x; a[3] += f.y - g.y;
  f = bf2f(h.z); g = bf2f(r.z); a[4] += f.x - g.x; a[5] += f.y - g.y;
  f = bf2f(h.w); g = bf2f(r.w); a[6] += f.x - g.x; a[7] += f.y - g.y;
}

// ---- one-shot prep kernel: r-chain (rfull->r1->r2, row-independent),
// weight transpose+bf16, entity cvt (with ent_ids fold-in), counts zero,
// BN-stat zero. Replaces 5 kernels + 1 memset.
__global__ __launch_bounds__(256) void k_prep(
    const float* __restrict__ coeff, const float* __restrict__ bases,
    const float* __restrict__ selfr, const float* __restrict__ relw1,
    const float* __restrict__ relw2,
    unsigned int* __restrict__ rfb, unsigned int* __restrict__ r1b,
    float* __restrict__ r2,
    const float* __restrict__ W1, const float* __restrict__ W2,
    unsigned short* __restrict__ WT1, unsigned short* __restrict__ WT2,
    const float* __restrict__ ent, const int* __restrict__ ent_ids,
    unsigned int* __restrict__ entbf,
    int* __restrict__ counts, float* __restrict__ stats,
    int nPairs, int nKeys, int cvtB, int cntB) {
  int b = blockIdx.x, tid = threadIdx.x;
  if (b < 201) {
    // relation chain: 2 rows per block; r2[row] depends only on rfull[row]
    __shared__ float row[2][128], r1row[2][128];
    int half = tid >> 7, c = tid & 127;
    int r = 2 * b + half;
    bool ok = (r <= 400);
    if (ok) {
      float v;
      if (r == 400) {
        v = selfr[c];
      } else {
        int rr = (r < 200) ? r : r - 200;
        float s = 0.f;
#pragma unroll 10
        for (int k = 0; k < 50; ++k) s += coeff[rr * 50 + k] * bases[k * 128 + c];
        v = (r < 200) ? s : -s;
      }
      row[half][c] = v;
    }
    __syncthreads();
    if (ok && c < 64) rfb[r * 64 + c] = pack2bf(row[half][2 * c], row[half][2 * c + 1]);
    if (ok) {
      float s = 0.f;
#pragma unroll 8
      for (int k = 0; k < 128; ++k) s += row[half][k] * relw1[k * 128 + c];
      r1row[half][c] = s;
    }
    __syncthreads();
    if (ok && c < 64) r1b[r * 64 + c] = pack2bf(r1row[half][2 * c], r1row[half][2 * c + 1]);
    if (ok) {
      float s = 0.f;
#pragma unroll 8
      for (int k = 0; k < 128; ++k) s += r1row[half][k] * relw2[k * 128 + c];
      r2[r * 128 + c] = s;
    }
  } else if (b < 585) {
    // weight transpose -> bf16
    int idx = (b - 201) * 256 + tid;
    const int half = 128 * 384;
    const float* W = (idx < half) ? W1 : W2;
    unsigned short* WT = (idx < half) ? WT1 : WT2;
    int id2 = (idx < half) ? idx : idx - half;
    int n = id2 & 127, k = id2 >> 7;
    int kk = k >> 7, kr = k & 127;
    WT[(size_t)n * 384 + k] = f2bf(W[(size_t)kk * 16384 + kr * 128 + n]);
  } else if (b < 585 + cvtB) {
    // entity table -> packed bf16, with ent_ids permutation folded in
    int i = (b - 585) * 256 + tid;
    if (i < nPairs) {
      int e = i >> 6;
      int src = ent_ids[e];
      float2 v = *(const float2*)&ent[(size_t)src * 128 + (i & 63) * 2];
      entbf[i] = pack2bf(v.x, v.y);
    }
  } else if (b < 585 + cvtB + cntB) {
    int i = (b - (585 + cvtB)) * 256 + tid;
    if (i < nKeys) counts[i] = 0;
  } else {
    stats[tid] = 0.f;          // sums1/sumsq1/sums2/sumsq2 = 512 floats
    stats[tid + 256] = 0.f;
  }
}

// ---- CSR build (unchanged, range-partitioned) ----
__global__ __launch_bounds__(256) void k_histR(const int* __restrict__ ei, const int* __restrict__ y,
                                               int* __restrict__ counts, int nE, int rsz) {
  int r = blockIdx.x;
  int e0 = blockIdx.y * 1024;
#pragma unroll
  for (int i = 0; i < 4; ++i) {
    int e = e0 + i * 256 + threadIdx.x;
    if (e < nE) {
      int key = ei[nE + e] * 3 + y[e];
      if (key / rsz == r) atomicAdd(&counts[key], 1);
    }
  }
}

__global__ void k_scan1(const int* __restrict__ counts, int* __restrict__ local,
                        int* __restrict__ blockSums, int n) {
  __shared__ int sdata[1024];
  int tid = threadIdx.x;
  int i = blockIdx.x * 1024 + tid;
  int v = (i < n) ? counts[i] : 0;
  sdata[tid] = v;
  __syncthreads();
  for (int off = 1; off < 1024; off <<= 1) {
    int t = (tid >= off) ? sdata[tid - off] : 0;
    __syncthreads();
    sdata[tid] += t;
    __syncthreads();
  }
  if (i < n) local[i] = sdata[tid] - v;
  if (tid == 1023) blockSums[blockIdx.x] = sdata[1023];
}

__global__ void k_scan2(const int* __restrict__ blockSums, int* __restrict__ carries,
                        int* __restrict__ offsets, int n, int nb) {
  __shared__ int sdata[1024];
  int tid = threadIdx.x;
  int v = (tid < nb) ? blockSums[tid] : 0;
  sdata[tid] = v;
  __syncthreads();
  for (int off = 1; off < 1024; off <<= 1) {
    int t = (tid >= off) ? sdata[tid - off] : 0;
    __syncthreads();
    sdata[tid] += t;
    __syncthreads();
  }
  if (tid < nb) carries[tid] = sdata[tid] - v;
  if (tid == 1023) offsets[n] = sdata[1023];
}

__global__ void k_scan3(const int* __restrict__ local, const int* __restrict__ carries,
                        int* __restrict__ offsets, int* __restrict__ cursor, int n) {
  int i = blockIdx.x * 1024 + threadIdx.x;
  if (i >= n) return;
  int v = local[i] + carries[blockIdx.x];
  offsets[i] = v;
  cursor[i] = v;
}

__global__ __launch_bounds__(256) void k_fillR(const int* __restrict__ ei, const int* __restrict__ et,
                                               const int* __restrict__ y, int* __restrict__ cursor,
                                               unsigned int* __restrict__ bucket, int nE, int rsz) {
  int r = blockIdx.x;
  int e0 = blockIdx.y * 1024;
#pragma unroll
  for (int i = 0; i < 4; ++i) {
    int e = e0 + i * 256 + threadIdx.x;
    if (e < nE) {
      int key = ei[nE + e] * 3 + y[e];
      if (key / rsz == r) {
        int slot = atomicAdd(&cursor[key], 1);
        bucket[slot] = (unsigned int)ei[e] | ((unsigned int)et[e] << 20);
      }
    }
  }
}

// ---- FUSED gather-aggregate + GEMM + BN-stats.  Eliminates the T round-trip
// (75 MB write + 77 MB read per layer).  BM=64: 192 keys aggregated into a
// 64x384 bf16 LDS tile (16 quads x 12 keys), then MFMA 64x128x384 with the
// B operand (WT, 98 KB, L2-resident) streamed straight from global.
// LDS row stride 392 shorts (16B-granule count 49, odd) -> even 8-lane/group
// b128 reads (conflict-free equivalent).  ~50.7 KB LDS -> 3 blocks/CU.
__global__ __launch_bounds__(256, 3) void k_fused(
    const unsigned int* __restrict__ xb, const unsigned int* __restrict__ rb,
    const int* __restrict__ offsets, const unsigned int* __restrict__ packed,
    const unsigned short* __restrict__ WT, unsigned short* __restrict__ C,
    float* __restrict__ sums, float* __restrict__ sumsq, int M) {
  __shared__ unsigned short As[64][392];
  __shared__ float sSum[128], sSq[128];
  const int tid = threadIdx.x;
  const int m0 = blockIdx.x * 64;
  const int wave = tid >> 6, lane = tid & 63;
  const int quad = lane >> 4, l16 = lane & 15;
  const int qid = (wave << 2) | quad;
  if (tid < 128) { sSum[tid] = 0.f; sSq[tid] = 0.f; }

  // ---- aggregation phase: each quad-group owns 12 consecutive keys ----
#pragma unroll 1
  for (int i = 0; i < 12; ++i) {
    int kloc = qid * 12 + i;                 // 0..191
    int dloc = kloc / 3, cls = kloc - dloc * 3;
    float a0[8] = {}, a1[8] = {};
    int dst = m0 + dloc;
    if (dst < M) {
      int key = dst * 3 + cls;
      int s = offsets[key], e = offsets[key + 1];
      int j = s;
      for (; j + 1 < e; j += 2) {
        unsigned int p0 = packed[j], p1 = packed[j + 1];
        int s0 = p0 & 0xFFFFF, t0 = p0 >> 20;
        int s1 = p1 & 0xFFFFF, t1 = p1 >> 20;
        uint4 h0 = *(const uint4*)&xb[(size_t)s0 * 64 + l16 * 4];
        uint4 r0 = *(const uint4*)&rb[(size_t)t0 * 64 + l16 * 4];
        uint4 h1 = *(const uint4*)&xb[(size_t)s1 * 64 + l16 * 4];
        uint4 r1 = *(const uint4*)&rb[(size_t)t1 * 64 + l16 * 4];
        acc8(a0, h0, r0);
        acc8(a1, h1, r1);
      }
      if (j < e) {
        unsigned int p0 = packed[j];
        int s0 = p0 & 0xFFFFF, t0 = p0 >> 20;
        uint4 h0 = *(const uint4*)&xb[(size_t)s0 * 64 + l16 * 4];
        uint4 r0 = *(const uint4*)&rb[(size_t)t0 * 64 + l16 * 4];
        acc8(a0, h0, r0);
      }
    }
    uint4 o;
    o.x = pack2bf(a0[0] + a1[0], a0[1] + a1[1]);
    o.y = pack2bf(a0[2] + a1[2], a0[3] + a1[3]);
    o.z = pack2bf(a0[4] + a1[4], a0[5] + a1[5]);
    o.w = pack2bf(a0[6] + a1[6], a0[7] + a1[7]);
    *(uint4*)&As[dloc][cls * 128 + l16 * 8] = o;   // OOB dst writes zeros
  }
  __syncthreads();

  // ---- GEMM phase: C[64x128] = As[64x384] @ WT^T, B streamed from L2 ----
  const unsigned short* Wp = WT + (size_t)(wave * 32 + l16) * 384 + quad * 8;
  short8 bc0 = *(const short8*)(Wp);
  short8 bc1 = *(const short8*)(Wp + 16 * 384);
  f32x4 acc[4][2] = {};
#pragma unroll 1
  for (int it = 0; it < 12; ++it) {
    short8 bn0, bn1;
    if (it < 11) {
      bn0 = *(const short8*)(Wp + (it + 1) * 32);
      bn1 = *(const short8*)(Wp + 16 * 384 + (it + 1) * 32);
    }
    short8 a[4];
#pragma unroll
    for (int t = 0; t < 4; ++t) a[t] = *(const short8*)&As[t * 16 + l16][it * 32 + quad * 8];
#pragma unroll
    for (int t = 0; t < 4; ++t) {
      acc[t][0] = __builtin_amdgcn_mfma_f32_16x16x32_bf16(a[t], bc0, acc[t][0], 0, 0, 0);
      acc[t][1] = __builtin_amdgcn_mfma_f32_16x16x32_bf16(a[t], bc1, acc[t][1], 0, 0, 0);
    }
    if (it < 11) { bc0 = bn0; bc1 = bn1; }
  }

  // ---- epilogue: bf16 C store + BN stats ----
  float ps[2] = {}, pq[2] = {};
#pragma unroll
  for (int t = 0; t < 4; ++t) {
#pragma unroll
    for (int reg = 0; reg < 4; ++reg) {
      int m = m0 + t * 16 + quad * 4 + reg;
      if (m < M) {
#pragma unroll
        for (int ct = 0; ct < 2; ++ct) {
          float v = acc[t][ct][reg];
          int col = wave * 32 + ct * 16 + l16;
          C[(size_t)m * 128 + col] = f2bf(v);
          ps[ct] += v; pq[ct] += v * v;
        }
      }
    }
  }
#pragma unroll
  for (int ct = 0; ct < 2; ++ct) {
    int col = wave * 32 + ct * 16 + l16;
    atomicAdd(&sSum[col], ps[ct]);
    atomicAdd(&sSq[col], pq[ct]);
  }
  __syncthreads();
  if (tid < 128) {
    atomicAdd(&sums[tid], sSum[tid]);
    atomicAdd(&sumsq[tid], sSq[tid]);
  }
}

// norm + tanh, uint4-vectorized (4 bf16-pairs per thread)
__global__ void k_norm(const uint4* __restrict__ Cb4,
                       const float* __restrict__ sums, const float* __restrict__ sumsq,
                       const float* __restrict__ gamma, const float* __restrict__ beta,
                       float invN, uint4* __restrict__ xb4, int nQuad) {
  __shared__ float sc_s[128], bi_s[128];
  if (threadIdx.x < 128) {
    int c = threadIdx.x;
    float mean = sums[c] * invN;
    float var = fmaxf(sumsq[c] * invN - mean * mean, 0.f);
    float sc = rsqrtf(var + 1e-5f) * gamma[c];
    sc_s[c] = sc;
    bi_s[c] = beta[c] - mean * sc;
  }
  __syncthreads();
  int i = blockIdx.x * blockDim.x + threadIdx.x;
  if (i >= nQuad) return;
  uint4 v = Cb4[i];
  int j = (i * 4) & 63;   // pair-col of v.x (4|64 -> stays within the row)
  uint4 o;
  float2 f;
  f = bf2f(v.x);
  o.x = pack2bf(tanhf(fmaf(f.x, sc_s[2*j],   bi_s[2*j])),   tanhf(fmaf(f.y, sc_s[2*j+1], bi_s[2*j+1])));
  f = bf2f(v.y);
  o.y = pack2bf(tanhf(fmaf(f.x, sc_s[2*j+2], bi_s[2*j+2])), tanhf(fmaf(f.y, sc_s[2*j+3], bi_s[2*j+3])));
  f = bf2f(v.z);
  o.z = pack2bf(tanhf(fmaf(f.x, sc_s[2*j+4], bi_s[2*j+4])), tanhf(fmaf(f.y, sc_s[2*j+5], bi_s[2*j+5])));
  f = bf2f(v.w);
  o.w = pack2bf(tanhf(fmaf(f.x, sc_s[2*j+6], bi_s[2*j+6])), tanhf(fmaf(f.y, sc_s[2*j+7], bi_s[2*j+7])));
  xb4[i] = o;
}

// one wave per triple: sum_d |x[h]+r[rel]-x[t]|
__global__ void k_score(const unsigned int* __restrict__ xb, const float* __restrict__ r,
                        const int* __restrict__ triples, float* __restrict__ out, int nT) {
  int gid = blockIdx.x * blockDim.x + threadIdx.x;
  int t = gid >> 6;
  if (t >= nT) return;
  int lane = gid & 63;
  int h = triples[t * 3], rel = triples[t * 3 + 1], tl = triples[t * 3 + 2];
  float2 a = bf2f(xb[(size_t)h * 64 + lane]);
  float2 b = *(const float2*)&r[(size_t)rel * 128 + lane * 2];
  float2 cc = bf2f(xb[(size_t)tl * 64 + lane]);
  float s = fabsf(a.x + b.x - cc.x) + fabsf(a.y + b.y - cc.y);
#pragma unroll
  for (int off = 32; off > 0; off >>= 1) s += __shfl_down(s, off);
  if (lane == 0) out[t] = s;
}

extern "C" void kernel_launch(void* const* d_in, const int* in_sizes, int n_in,
                              void* d_out, int out_size, void* d_ws, size_t ws_size,
                              hipStream_t stream) {
  const float* ent   = (const float*)d_in[0];
  const float* bases = (const float*)d_in[1];
  const float* coeff = (const float*)d_in[2];
  const float* selfr = (const float*)d_in[3];
  const float* W1    = (const float*)d_in[4];
  const float* relw1 = (const float*)d_in[5];
  const float* g1    = (const float*)d_in[6];
  const float* b1    = (const float*)d_in[7];
  const float* W2    = (const float*)d_in[8];
  const float* relw2 = (const float*)d_in[9];
  const float* g2    = (const float*)d_in[10];
  const float* b2    = (const float*)d_in[11];
  const int* ent_ids = (const int*)d_in[12];
  const int* ei      = (const int*)d_in[13];
  const int* et      = (const int*)d_in[14];
  const int* yk      = (const int*)d_in[15];
  const int* triples = (const int*)d_in[16];

  const int M  = in_sizes[0] / 128;   // 100000
  const int nE = in_sizes[14];        // 800000
  const int nT = in_sizes[16] / 3;    // 4096
  const int nKeys = M * 3;
  const int nScanBlocks = (nKeys + 1023) / 1024;
  const int rsz = (nKeys + 7) / 8;

  // workspace layout (~88 MB; entbf no longer aliases Cb — fused kernel
  // reads the table and writes C in the same dispatch)
  float* p = (float*)d_ws;
  float* r2    = p; p += 401 * 128;
  float* stats = p; p += 512;          // sums1|sumsq1|sums2|sumsq2
  unsigned short* Cb  = (unsigned short*)p;                       // M*128 bf16
  unsigned int* entbf = (unsigned int*)(Cb + (size_t)M * 128);    // M*64
  unsigned int* xb    = entbf + (size_t)M * 64;                   // M*64
  unsigned int* rfb   = xb + (size_t)M * 64;                      // 401*64
  unsigned int* r1b   = rfb + 401 * 64;                           // 401*64
  unsigned short* WT1 = (unsigned short*)(r1b + 401 * 64);
  unsigned short* WT2 = WT1 + 128 * 384;
  int* counts  = (int*)(WT2 + 128 * 384);
  int* offsets = counts + nKeys;
  int* cursor  = offsets + nKeys + 1;
  int* slocal  = cursor + nKeys;
  int* sblock  = slocal + nKeys;
  int* scarry  = sblock + nScanBlocks;
  unsigned int* bucket = (unsigned int*)(scarry + nScanBlocks);

  float* sums1 = stats, *sumsq1 = stats + 128;
  float* sums2 = stats + 256, *sumsq2 = stats + 384;
  float* out = (float*)d_out;

  const int nPairs = M * 64;
  const int nQuad  = M * 16;
  const int cvtB = (nPairs + 255) / 256;
  const int cntB = (nKeys + 255) / 256;
  const int prepBlocks = 585 + cvtB + cntB + 1;
  const int fusedBlocks = (M + 63) / 64;
  const int normBlocks = (nQuad + 255) / 256;
  const dim3 rangedGrid(8, (nE + 1023) / 1024);

  // one prep dispatch: r-chain, weight cvt, entity cvt (+ent_ids fold),
  // counts zero, stat zero
  k_prep<<<prepBlocks, 256, 0, stream>>>(coeff, bases, selfr, relw1, relw2,
                                         rfb, r1b, r2, W1, W2, WT1, WT2,
                                         ent, ent_ids, entbf, counts, stats,
                                         nPairs, nKeys, cvtB, cntB);

  // CSR over (dst, class)
  k_histR<<<rangedGrid, 256, 0, stream>>>(ei, yk, counts, nE, rsz);
  k_scan1<<<nScanBlocks, 1024, 0, stream>>>(counts, slocal, sblock, nKeys);
  k_scan2<<<1, 1024, 0, stream>>>(sblock, scarry, offsets, nKeys, nScanBlocks);
  k_scan3<<<nScanBlocks, 1024, 0, stream>>>(slocal, scarry, offsets, cursor, nKeys);
  k_fillR<<<rangedGrid, 256, 0, stream>>>(ei, et, yk, cursor, bucket, nE, rsz);

  // ---- layer 1 (fused agg+GEMM+stats) ----
  k_fused<<<fusedBlocks, 256, 0, stream>>>(entbf, rfb, offsets, bucket, WT1,
                                           Cb, sums1, sumsq1, M);
  k_norm<<<normBlocks, 256, 0, stream>>>((const uint4*)Cb, sums1, sumsq1, g1, b1,
                                         1.0f / M, (uint4*)xb, nQuad);

  // ---- layer 2 ----
  k_fused<<<fusedBlocks, 256, 0, stream>>>(xb, r1b, offsets, bucket, WT2,
                                           Cb, sums2, sumsq2, M);
  k_norm<<<normBlocks, 256, 0, stream>>>((const uint4*)Cb, sums2, sumsq2, g2, b2,
                                         1.0f / M, (uint4*)xb, nQuad);

  // ---- scoring ----
  k_score<<<(nT * 64 + 255) / 256, 256, 0, stream>>>(xb, r2, triples, out, nT);
}

// Round 3
// 497.495 us; speedup vs baseline: 1.0114x; 1.0114x over previous
//
#include <hip/hip_runtime.h>
#include <cstdint>

typedef __attribute__((ext_vector_type(8))) short short8;
typedef __attribute__((ext_vector_type(4))) float f32x4;

static __device__ __forceinline__ unsigned short f2bf(float f) {
  unsigned int u = __float_as_uint(f);
  unsigned int r = (u + 0x7FFFu + ((u >> 16) & 1u)) >> 16;   // RNE
  return (unsigned short)r;
}
static __device__ __forceinline__ unsigned int pack2bf(float a, float b) {
  return (unsigned int)f2bf(a) | ((unsigned int)f2bf(b) << 16);
}
static __device__ __forceinline__ float2 bf2f(unsigned int u) {
  return make_float2(__uint_as_float(u << 16), __uint_as_float(u & 0xFFFF0000u));
}
static __device__ __forceinline__ void acc8(float* a, uint4 h, uint4 r) {
  float2 f, g;
  f = bf2f(h.x); g = bf2f(r.x); a[0] += f.x - g.x; a[1] += f.y - g.y;
  f = bf2f(h.y); g = bf2f(r.y); a[2] += f.x - g.x; a[3] += f.y - g.y;
  f = bf2f(h.z); g = bf2f(r.z); a[4] += f.x - g.x; a[5] += f.y - g.y;
  f = bf2f(h.w); g = bf2f(r.w); a[6] += f.x - g.x; a[7] += f.y - g.y;
}

// ---- one-shot prep kernel: r-chain (rfull->r1->r2, row-independent),
// weight transpose+bf16, entity cvt (with ent_ids fold-in), counts zero,
// BN-stat zero. Replaces 5 kernels + 1 memset.
__global__ __launch_bounds__(256) void k_prep(
    const float* __restrict__ coeff, const float* __restrict__ bases,
    const float* __restrict__ selfr, const float* __restrict__ relw1,
    const float* __restrict__ relw2,
    unsigned int* __restrict__ rfb, unsigned int* __restrict__ r1b,
    float* __restrict__ r2,
    const float* __restrict__ W1, const float* __restrict__ W2,
    unsigned short* __restrict__ WT1, unsigned short* __restrict__ WT2,
    const float* __restrict__ ent, const int* __restrict__ ent_ids,
    unsigned int* __restrict__ entbf,
    int* __restrict__ counts, float* __restrict__ stats,
    int nPairs, int nKeys, int cvtB, int cntB) {
  int b = blockIdx.x, tid = threadIdx.x;
  if (b < 201) {
    // relation chain: 2 rows per block; r2[row] depends only on rfull[row]
    __shared__ float row[2][128], r1row[2][128];
    int half = tid >> 7, c = tid & 127;
    int r = 2 * b + half;
    bool ok = (r <= 400);
    if (ok) {
      float v;
      if (r == 400) {
        v = selfr[c];
      } else {
        int rr = (r < 200) ? r : r - 200;
        float s = 0.f;
#pragma unroll 10
        for (int k = 0; k < 50; ++k) s += coeff[rr * 50 + k] * bases[k * 128 + c];
        v = (r < 200) ? s : -s;
      }
      row[half][c] = v;
    }
    __syncthreads();
    if (ok && c < 64) rfb[r * 64 + c] = pack2bf(row[half][2 * c], row[half][2 * c + 1]);
    if (ok) {
      float s = 0.f;
#pragma unroll 8
      for (int k = 0; k < 128; ++k) s += row[half][k] * relw1[k * 128 + c];
      r1row[half][c] = s;
    }
    __syncthreads();
    if (ok && c < 64) r1b[r * 64 + c] = pack2bf(r1row[half][2 * c], r1row[half][2 * c + 1]);
    if (ok) {
      float s = 0.f;
#pragma unroll 8
      for (int k = 0; k < 128; ++k) s += r1row[half][k] * relw2[k * 128 + c];
      r2[r * 128 + c] = s;
    }
  } else if (b < 585) {
    // weight transpose -> bf16
    int idx = (b - 201) * 256 + tid;
    const int half = 128 * 384;
    const float* W = (idx < half) ? W1 : W2;
    unsigned short* WT = (idx < half) ? WT1 : WT2;
    int id2 = (idx < half) ? idx : idx - half;
    int n = id2 & 127, k = id2 >> 7;
    int kk = k >> 7, kr = k & 127;
    WT[(size_t)n * 384 + k] = f2bf(W[(size_t)kk * 16384 + kr * 128 + n]);
  } else if (b < 585 + cvtB) {
    // entity table -> packed bf16, with ent_ids permutation folded in
    int i = (b - 585) * 256 + tid;
    if (i < nPairs) {
      int e = i >> 6;
      int src = ent_ids[e];
      float2 v = *(const float2*)&ent[(size_t)src * 128 + (i & 63) * 2];
      entbf[i] = pack2bf(v.x, v.y);
    }
  } else if (b < 585 + cvtB + cntB) {
    int i = (b - (585 + cvtB)) * 256 + tid;
    if (i < nKeys) counts[i] = 0;
  } else {
    stats[tid] = 0.f;          // sums1/sumsq1/sums2/sumsq2 = 512 floats
    stats[tid + 256] = 0.f;
  }
}

// ---- CSR build (unchanged, range-partitioned) ----
__global__ __launch_bounds__(256) void k_histR(const int* __restrict__ ei, const int* __restrict__ y,
                                               int* __restrict__ counts, int nE, int rsz) {
  int r = blockIdx.x;
  int e0 = blockIdx.y * 1024;
#pragma unroll
  for (int i = 0; i < 4; ++i) {
    int e = e0 + i * 256 + threadIdx.x;
    if (e < nE) {
      int key = ei[nE + e] * 3 + y[e];
      if (key / rsz == r) atomicAdd(&counts[key], 1);
    }
  }
}

__global__ void k_scan1(const int* __restrict__ counts, int* __restrict__ local,
                        int* __restrict__ blockSums, int n) {
  __shared__ int sdata[1024];
  int tid = threadIdx.x;
  int i = blockIdx.x * 1024 + tid;
  int v = (i < n) ? counts[i] : 0;
  sdata[tid] = v;
  __syncthreads();
  for (int off = 1; off < 1024; off <<= 1) {
    int t = (tid >= off) ? sdata[tid - off] : 0;
    __syncthreads();
    sdata[tid] += t;
    __syncthreads();
  }
  if (i < n) local[i] = sdata[tid] - v;
  if (tid == 1023) blockSums[blockIdx.x] = sdata[1023];
}

__global__ void k_scan2(const int* __restrict__ blockSums, int* __restrict__ carries,
                        int* __restrict__ offsets, int n, int nb) {
  __shared__ int sdata[1024];
  int tid = threadIdx.x;
  int v = (tid < nb) ? blockSums[tid] : 0;
  sdata[tid] = v;
  __syncthreads();
  for (int off = 1; off < 1024; off <<= 1) {
    int t = (tid >= off) ? sdata[tid - off] : 0;
    __syncthreads();
    sdata[tid] += t;
    __syncthreads();
  }
  if (tid < nb) carries[tid] = sdata[tid] - v;
  if (tid == 1023) offsets[n] = sdata[1023];
}

__global__ void k_scan3(const int* __restrict__ local, const int* __restrict__ carries,
                        int* __restrict__ offsets, int* __restrict__ cursor, int n) {
  int i = blockIdx.x * 1024 + threadIdx.x;
  if (i >= n) return;
  int v = local[i] + carries[blockIdx.x];
  offsets[i] = v;
  cursor[i] = v;
}

__global__ __launch_bounds__(256) void k_fillR(const int* __restrict__ ei, const int* __restrict__ et,
                                               const int* __restrict__ y, int* __restrict__ cursor,
                                               unsigned int* __restrict__ bucket, int nE, int rsz) {
  int r = blockIdx.x;
  int e0 = blockIdx.y * 1024;
#pragma unroll
  for (int i = 0; i < 4; ++i) {
    int e = e0 + i * 256 + threadIdx.x;
    if (e < nE) {
      int key = ei[nE + e] * 3 + y[e];
      if (key / rsz == r) {
        int slot = atomicAdd(&cursor[key], 1);
        bucket[slot] = (unsigned int)ei[e] | ((unsigned int)et[e] << 20);
      }
    }
  }
}

// ---- FUSED gather-aggregate + GEMM + BN-stats, BM=32.
// Round-2 lesson: BM=64 (50KB LDS, 3 blk/CU, 24% occ) strangled the
// latency-bound gather (55->135us). BM=32: 25KB LDS + 1KB stats ->
// 6 blocks/CU = 24 waves = 75% occupancy; acc[2][2] keeps VGPR ~60
// (< 85 required by 6 waves/SIMD). WT (98KB) streamed from L2 per block;
// aggregate 307MB of L2 reads ~ 9us, overlapped across desynced blocks.
__global__ __launch_bounds__(256, 6) void k_fused(
    const unsigned int* __restrict__ xb, const unsigned int* __restrict__ rb,
    const int* __restrict__ offsets, const unsigned int* __restrict__ packed,
    const unsigned short* __restrict__ WT, unsigned short* __restrict__ C,
    float* __restrict__ sums, float* __restrict__ sumsq, int M) {
  __shared__ unsigned short As[32][392];
  __shared__ float sSum[128], sSq[128];
  const int tid = threadIdx.x;
  const int m0 = blockIdx.x * 32;
  const int wave = tid >> 6, lane = tid & 63;
  const int quad = lane >> 4, l16 = lane & 15;
  const int qid = (wave << 2) | quad;
  if (tid < 128) { sSum[tid] = 0.f; sSq[tid] = 0.f; }

  // ---- aggregation phase: each quad-group owns 6 consecutive keys ----
#pragma unroll 1
  for (int i = 0; i < 6; ++i) {
    int kloc = qid * 6 + i;                  // 0..95
    int dloc = kloc / 3, cls = kloc - dloc * 3;
    float a0[8] = {}, a1[8] = {};
    int dst = m0 + dloc;
    if (dst < M) {
      int key = dst * 3 + cls;
      int s = offsets[key], e = offsets[key + 1];
      int j = s;
      for (; j + 1 < e; j += 2) {
        unsigned int p0 = packed[j], p1 = packed[j + 1];
        int s0 = p0 & 0xFFFFF, t0 = p0 >> 20;
        int s1 = p1 & 0xFFFFF, t1 = p1 >> 20;
        uint4 h0 = *(const uint4*)&xb[(size_t)s0 * 64 + l16 * 4];
        uint4 r0 = *(const uint4*)&rb[(size_t)t0 * 64 + l16 * 4];
        uint4 h1 = *(const uint4*)&xb[(size_t)s1 * 64 + l16 * 4];
        uint4 r1 = *(const uint4*)&rb[(size_t)t1 * 64 + l16 * 4];
        acc8(a0, h0, r0);
        acc8(a1, h1, r1);
      }
      if (j < e) {
        unsigned int p0 = packed[j];
        int s0 = p0 & 0xFFFFF, t0 = p0 >> 20;
        uint4 h0 = *(const uint4*)&xb[(size_t)s0 * 64 + l16 * 4];
        uint4 r0 = *(const uint4*)&rb[(size_t)t0 * 64 + l16 * 4];
        acc8(a0, h0, r0);
      }
    }
    uint4 o;
    o.x = pack2bf(a0[0] + a1[0], a0[1] + a1[1]);
    o.y = pack2bf(a0[2] + a1[2], a0[3] + a1[3]);
    o.z = pack2bf(a0[4] + a1[4], a0[5] + a1[5]);
    o.w = pack2bf(a0[6] + a1[6], a0[7] + a1[7]);
    *(uint4*)&As[dloc][cls * 128 + l16 * 8] = o;   // OOB dst writes zeros
  }
  __syncthreads();

  // ---- GEMM phase: C[32x128] = As[32x384] @ WT^T, B streamed from L2 ----
  // wave w owns output cols w*32..w*32+31 (2 col-frags), all 32 rows (2 row-frags)
  const unsigned short* Wp = WT + (size_t)(wave * 32 + l16) * 384 + quad * 8;
  short8 bc0 = *(const short8*)(Wp);
  short8 bc1 = *(const short8*)(Wp + 16 * 384);
  f32x4 acc[2][2] = {};
#pragma unroll 1
  for (int it = 0; it < 12; ++it) {
    short8 bn0, bn1;
    if (it < 11) {
      bn0 = *(const short8*)(Wp + (it + 1) * 32);
      bn1 = *(const short8*)(Wp + 16 * 384 + (it + 1) * 32);
    }
    short8 a[2];
#pragma unroll
    for (int t = 0; t < 2; ++t) a[t] = *(const short8*)&As[t * 16 + l16][it * 32 + quad * 8];
#pragma unroll
    for (int t = 0; t < 2; ++t) {
      acc[t][0] = __builtin_amdgcn_mfma_f32_16x16x32_bf16(a[t], bc0, acc[t][0], 0, 0, 0);
      acc[t][1] = __builtin_amdgcn_mfma_f32_16x16x32_bf16(a[t], bc1, acc[t][1], 0, 0, 0);
    }
    if (it < 11) { bc0 = bn0; bc1 = bn1; }
  }

  // ---- epilogue: bf16 C store + BN stats ----
  float ps[2] = {}, pq[2] = {};
#pragma unroll
  for (int t = 0; t < 2; ++t) {
#pragma unroll
    for (int reg = 0; reg < 4; ++reg) {
      int m = m0 + t * 16 + quad * 4 + reg;
      if (m < M) {
#pragma unroll
        for (int ct = 0; ct < 2; ++ct) {
          float v = acc[t][ct][reg];
          int col = wave * 32 + ct * 16 + l16;
          C[(size_t)m * 128 + col] = f2bf(v);
          ps[ct] += v; pq[ct] += v * v;
        }
      }
    }
  }
#pragma unroll
  for (int ct = 0; ct < 2; ++ct) {
    int col = wave * 32 + ct * 16 + l16;
    atomicAdd(&sSum[col], ps[ct]);
    atomicAdd(&sSq[col], pq[ct]);
  }
  __syncthreads();
  if (tid < 128) {
    atomicAdd(&sums[tid], sSum[tid]);
    atomicAdd(&sumsq[tid], sSq[tid]);
  }
}

// norm + tanh, uint4-vectorized (4 bf16-pairs per thread)
__global__ void k_norm(const uint4* __restrict__ Cb4,
                       const float* __restrict__ sums, const float* __restrict__ sumsq,
                       const float* __restrict__ gamma, const float* __restrict__ beta,
                       float invN, uint4* __restrict__ xb4, int nQuad) {
  __shared__ float sc_s[128], bi_s[128];
  if (threadIdx.x < 128) {
    int c = threadIdx.x;
    float mean = sums[c] * invN;
    float var = fmaxf(sumsq[c] * invN - mean * mean, 0.f);
    float sc = rsqrtf(var + 1e-5f) * gamma[c];
    sc_s[c] = sc;
    bi_s[c] = beta[c] - mean * sc;
  }
  __syncthreads();
  int i = blockIdx.x * blockDim.x + threadIdx.x;
  if (i >= nQuad) return;
  uint4 v = Cb4[i];
  int j = (i * 4) & 63;   // pair-col of v.x (4|64 -> stays within the row)
  uint4 o;
  float2 f;
  f = bf2f(v.x);
  o.x = pack2bf(tanhf(fmaf(f.x, sc_s[2*j],   bi_s[2*j])),   tanhf(fmaf(f.y, sc_s[2*j+1], bi_s[2*j+1])));
  f = bf2f(v.y);
  o.y = pack2bf(tanhf(fmaf(f.x, sc_s[2*j+2], bi_s[2*j+2])), tanhf(fmaf(f.y, sc_s[2*j+3], bi_s[2*j+3])));
  f = bf2f(v.z);
  o.z = pack2bf(tanhf(fmaf(f.x, sc_s[2*j+4], bi_s[2*j+4])), tanhf(fmaf(f.y, sc_s[2*j+5], bi_s[2*j+5])));
  f = bf2f(v.w);
  o.w = pack2bf(tanhf(fmaf(f.x, sc_s[2*j+6], bi_s[2*j+6])), tanhf(fmaf(f.y, sc_s[2*j+7], bi_s[2*j+7])));
  xb4[i] = o;
}

// one wave per triple: sum_d |x[h]+r[rel]-x[t]|
__global__ void k_score(const unsigned int* __restrict__ xb, const float* __restrict__ r,
                        const int* __restrict__ triples, float* __restrict__ out, int nT) {
  int gid = blockIdx.x * blockDim.x + threadIdx.x;
  int t = gid >> 6;
  if (t >= nT) return;
  int lane = gid & 63;
  int h = triples[t * 3], rel = triples[t * 3 + 1], tl = triples[t * 3 + 2];
  float2 a = bf2f(xb[(size_t)h * 64 + lane]);
  float2 b = *(const float2*)&r[(size_t)rel * 128 + lane * 2];
  float2 cc = bf2f(xb[(size_t)tl * 64 + lane]);
  float s = fabsf(a.x + b.x - cc.x) + fabsf(a.y + b.y - cc.y);
#pragma unroll
  for (int off = 32; off > 0; off >>= 1) s += __shfl_down(s, off);
  if (lane == 0) out[t] = s;
}

extern "C" void kernel_launch(void* const* d_in, const int* in_sizes, int n_in,
                              void* d_out, int out_size, void* d_ws, size_t ws_size,
                              hipStream_t stream) {
  const float* ent   = (const float*)d_in[0];
  const float* bases = (const float*)d_in[1];
  const float* coeff = (const float*)d_in[2];
  const float* selfr = (const float*)d_in[3];
  const float* W1    = (const float*)d_in[4];
  const float* relw1 = (const float*)d_in[5];
  const float* g1    = (const float*)d_in[6];
  const float* b1    = (const float*)d_in[7];
  const float* W2    = (const float*)d_in[8];
  const float* relw2 = (const float*)d_in[9];
  const float* g2    = (const float*)d_in[10];
  const float* b2    = (const float*)d_in[11];
  const int* ent_ids = (const int*)d_in[12];
  const int* ei      = (const int*)d_in[13];
  const int* et      = (const int*)d_in[14];
  const int* yk      = (const int*)d_in[15];
  const int* triples = (const int*)d_in[16];

  const int M  = in_sizes[0] / 128;   // 100000
  const int nE = in_sizes[14];        // 800000
  const int nT = in_sizes[16] / 3;    // 4096
  const int nKeys = M * 3;
  const int nScanBlocks = (nKeys + 1023) / 1024;
  const int rsz = (nKeys + 7) / 8;

  // workspace layout (~88 MB)
  float* p = (float*)d_ws;
  float* r2    = p; p += 401 * 128;
  float* stats = p; p += 512;          // sums1|sumsq1|sums2|sumsq2
  unsigned short* Cb  = (unsigned short*)p;                       // M*128 bf16
  unsigned int* entbf = (unsigned int*)(Cb + (size_t)M * 128);    // M*64
  unsigned int* xb    = entbf + (size_t)M * 64;                   // M*64
  unsigned int* rfb   = xb + (size_t)M * 64;                      // 401*64
  unsigned int* r1b   = rfb + 401 * 64;                           // 401*64
  unsigned short* WT1 = (unsigned short*)(r1b + 401 * 64);
  unsigned short* WT2 = WT1 + 128 * 384;
  int* counts  = (int*)(WT2 + 128 * 384);
  int* offsets = counts + nKeys;
  int* cursor  = offsets + nKeys + 1;
  int* slocal  = cursor + nKeys;
  int* sblock  = slocal + nKeys;
  int* scarry  = sblock + nScanBlocks;
  unsigned int* bucket = (unsigned int*)(scarry + nScanBlocks);

  float* sums1 = stats, *sumsq1 = stats + 128;
  float* sums2 = stats + 256, *sumsq2 = stats + 384;
  float* out = (float*)d_out;

  const int nPairs = M * 64;
  const int nQuad  = M * 16;
  const int cvtB = (nPairs + 255) / 256;
  const int cntB = (nKeys + 255) / 256;
  const int prepBlocks = 585 + cvtB + cntB + 1;
  const int fusedBlocks = (M + 31) / 32;
  const int normBlocks = (nQuad + 255) / 256;
  const dim3 rangedGrid(8, (nE + 1023) / 1024);

  // one prep dispatch: r-chain, weight cvt, entity cvt (+ent_ids fold),
  // counts zero, stat zero
  k_prep<<<prepBlocks, 256, 0, stream>>>(coeff, bases, selfr, relw1, relw2,
                                         rfb, r1b, r2, W1, W2, WT1, WT2,
                                         ent, ent_ids, entbf, counts, stats,
                                         nPairs, nKeys, cvtB, cntB);

  // CSR over (dst, class)
  k_histR<<<rangedGrid, 256, 0, stream>>>(ei, yk, counts, nE, rsz);
  k_scan1<<<nScanBlocks, 1024, 0, stream>>>(counts, slocal, sblock, nKeys);
  k_scan2<<<1, 1024, 0, stream>>>(sblock, scarry, offsets, nKeys, nScanBlocks);
  k_scan3<<<nScanBlocks, 1024, 0, stream>>>(slocal, scarry, offsets, cursor, nKeys);
  k_fillR<<<rangedGrid, 256, 0, stream>>>(ei, et, yk, cursor, bucket, nE, rsz);

  // ---- layer 1 (fused agg+GEMM+stats) ----
  k_fused<<<fusedBlocks, 256, 0, stream>>>(entbf, rfb, offsets, bucket, WT1,
                                           Cb, sums1, sumsq1, M);
  k_norm<<<normBlocks, 256, 0, stream>>>((const uint4*)Cb, sums1, sumsq1, g1, b1,
                                         1.0f / M, (uint4*)xb, nQuad);

  // ---- layer 2 ----
  k_fused<<<fusedBlocks, 256, 0, stream>>>(xb, r1b, offsets, bucket, WT2,
                                           Cb, sums2, sumsq2, M);
  k_norm<<<normBlocks, 256, 0, stream>>>((const uint4*)Cb, sums2, sumsq2, g2, b2,
                                         1.0f / M, (uint4*)xb, nQuad);

  // ---- scoring ----
  k_score<<<(nT * 64 + 255) / 256, 256, 0, stream>>>(xb, r2, triples, out, nT);
}

// Round 5
// 432.591 us; speedup vs baseline: 1.1632x; 1.1500x over previous
//
#include <hip/hip_runtime.h>
#include <cstdint>

typedef __attribute__((ext_vector_type(8))) short short8;
typedef __attribute__((ext_vector_type(4))) float f32x4;

static __device__ __forceinline__ unsigned short f2bf(float f) {
  unsigned int u = __float_as_uint(f);
  unsigned int r = (u + 0x7FFFu + ((u >> 16) & 1u)) >> 16;   // RNE
  return (unsigned short)r;
}
static __device__ __forceinline__ unsigned int pack2bf(float a, float b) {
  return (unsigned int)f2bf(a) | ((unsigned int)f2bf(b) << 16);
}
static __device__ __forceinline__ float2 bf2f(unsigned int u) {
  return make_float2(__uint_as_float(u << 16), __uint_as_float(u & 0xFFFF0000u));
}
static __device__ __forceinline__ void acc8(float* a, uint4 h, uint4 r) {
  float2 f, g;
  f = bf2f(h.x); g = bf2f(r.x); a[0] += f.x - g.x; a[1] += f.y - g.y;
  f = bf2f(h.y); g = bf2f(r.y); a[2] += f.x - g.x; a[3] += f.y - g.y;
  f = bf2f(h.z); g = bf2f(r.z); a[4] += f.x - g.x; a[5] += f.y - g.y;
  f = bf2f(h.w); g = bf2f(r.w); a[6] += f.x - g.x; a[7] += f.y - g.y;
}

// ---- one-shot prep kernel: r-chain, weight transpose+bf16, entity cvt
// (ent_ids folded), counts zero, stat zero (64 replicas + finals = 16896 f).
__global__ __launch_bounds__(256) void k_prep(
    const float* __restrict__ coeff, const float* __restrict__ bases,
    const float* __restrict__ selfr, const float* __restrict__ relw1,
    const float* __restrict__ relw2,
    unsigned int* __restrict__ rfb, unsigned int* __restrict__ r1b,
    float* __restrict__ r2,
    const float* __restrict__ W1, const float* __restrict__ W2,
    unsigned short* __restrict__ WT1, unsigned short* __restrict__ WT2,
    const float* __restrict__ ent, const int* __restrict__ ent_ids,
    unsigned int* __restrict__ entbf,
    int* __restrict__ counts, float* __restrict__ stats,
    int nPairs, int nKeys, int cvtB, int cntB) {
  int b = blockIdx.x, tid = threadIdx.x;
  if (b < 201) {
    // relation chain: 2 rows per block; r2[row] depends only on rfull[row]
    __shared__ float row[2][128], r1row[2][128];
    int half = tid >> 7, c = tid & 127;
    int r = 2 * b + half;
    bool ok = (r <= 400);
    if (ok) {
      float v;
      if (r == 400) {
        v = selfr[c];
      } else {
        int rr = (r < 200) ? r : r - 200;
        float s = 0.f;
#pragma unroll 10
        for (int k = 0; k < 50; ++k) s += coeff[rr * 50 + k] * bases[k * 128 + c];
        v = (r < 200) ? s : -s;
      }
      row[half][c] = v;
    }
    __syncthreads();
    if (ok && c < 64) rfb[r * 64 + c] = pack2bf(row[half][2 * c], row[half][2 * c + 1]);
    if (ok) {
      float s = 0.f;
#pragma unroll 8
      for (int k = 0; k < 128; ++k) s += row[half][k] * relw1[k * 128 + c];
      r1row[half][c] = s;
    }
    __syncthreads();
    if (ok && c < 64) r1b[r * 64 + c] = pack2bf(r1row[half][2 * c], r1row[half][2 * c + 1]);
    if (ok) {
      float s = 0.f;
#pragma unroll 8
      for (int k = 0; k < 128; ++k) s += r1row[half][k] * relw2[k * 128 + c];
      r2[r * 128 + c] = s;
    }
  } else if (b < 585) {
    // weight transpose -> bf16
    int idx = (b - 201) * 256 + tid;
    const int half = 128 * 384;
    const float* W = (idx < half) ? W1 : W2;
    unsigned short* WT = (idx < half) ? WT1 : WT2;
    int id2 = (idx < half) ? idx : idx - half;
    int n = id2 & 127, k = id2 >> 7;
    int kk = k >> 7, kr = k & 127;
    WT[(size_t)n * 384 + k] = f2bf(W[(size_t)kk * 16384 + kr * 128 + n]);
  } else if (b < 585 + cvtB) {
    // entity table -> packed bf16, with ent_ids permutation folded in
    int i = (b - 585) * 256 + tid;
    if (i < nPairs) {
      int e = i >> 6;
      int src = ent_ids[e];
      float2 v = *(const float2*)&ent[(size_t)src * 128 + (i & 63) * 2];
      entbf[i] = pack2bf(v.x, v.y);
    }
  } else if (b < 585 + cvtB + cntB) {
    int i = (b - (585 + cvtB)) * 256 + tid;
    if (i < nKeys) counts[i] = 0;
  } else {
    // zero 64 stat replicas (64*256) + 2 final blocks (512) = 16896 floats
    int i = (b - (585 + cvtB + cntB)) * 256 + tid;
    if (i < 16896) stats[i] = 0.f;
  }
}

// ---- CSR build (unchanged, range-partitioned) ----
__global__ __launch_bounds__(256) void k_histR(const int* __restrict__ ei, const int* __restrict__ y,
                                               int* __restrict__ counts, int nE, int rsz) {
  int r = blockIdx.x;
  int e0 = blockIdx.y * 1024;
#pragma unroll
  for (int i = 0; i < 4; ++i) {
    int e = e0 + i * 256 + threadIdx.x;
    if (e < nE) {
      int key = ei[nE + e] * 3 + y[e];
      if (key / rsz == r) atomicAdd(&counts[key], 1);
    }
  }
}

__global__ void k_scan1(const int* __restrict__ counts, int* __restrict__ local,
                        int* __restrict__ blockSums, int n) {
  __shared__ int sdata[1024];
  int tid = threadIdx.x;
  int i = blockIdx.x * 1024 + tid;
  int v = (i < n) ? counts[i] : 0;
  sdata[tid] = v;
  __syncthreads();
  for (int off = 1; off < 1024; off <<= 1) {
    int t = (tid >= off) ? sdata[tid - off] : 0;
    __syncthreads();
    sdata[tid] += t;
    __syncthreads();
  }
  if (i < n) local[i] = sdata[tid] - v;
  if (tid == 1023) blockSums[blockIdx.x] = sdata[1023];
}

__global__ void k_scan2(const int* __restrict__ blockSums, int* __restrict__ carries,
                        int* __restrict__ offsets, int n, int nb) {
  __shared__ int sdata[1024];
  int tid = threadIdx.x;
  int v = (tid < nb) ? blockSums[tid] : 0;
  sdata[tid] = v;
  __syncthreads();
  for (int off = 1; off < 1024; off <<= 1) {
    int t = (tid >= off) ? sdata[tid - off] : 0;
    __syncthreads();
    sdata[tid] += t;
    __syncthreads();
  }
  if (tid < nb) carries[tid] = sdata[tid] - v;
  if (tid == 1023) offsets[n] = sdata[1023];
}

__global__ void k_scan3(const int* __restrict__ local, const int* __restrict__ carries,
                        int* __restrict__ offsets, int* __restrict__ cursor, int n) {
  int i = blockIdx.x * 1024 + threadIdx.x;
  if (i >= n) return;
  int v = local[i] + carries[blockIdx.x];
  offsets[i] = v;
  cursor[i] = v;
}

__global__ __launch_bounds__(256) void k_fillR(const int* __restrict__ ei, const int* __restrict__ et,
                                               const int* __restrict__ y, int* __restrict__ cursor,
                                               unsigned int* __restrict__ bucket, int nE, int rsz) {
  int r = blockIdx.x;
  int e0 = blockIdx.y * 1024;
#pragma unroll
  for (int i = 0; i < 4; ++i) {
    int e = e0 + i * 256 + threadIdx.x;
    if (e < nE) {
      int key = ei[nE + e] * 3 + y[e];
      if (key / rsz == r) {
        int slot = atomicAdd(&cursor[key], 1);
        bucket[slot] = (unsigned int)ei[e] | ((unsigned int)et[e] << 20);
      }
    }
  }
}

// ---- FUSED gather-aggregate + GEMM + BN-stats, BM=32.
// R3 mapping restored (harness-verified): 16 quad-groups (4 waves x 4 quads),
// each owns 6 consecutive keys = 2 dst rows; 96 keys = full 32-row tile.
// R4 lesson: there are only 16 quad-groups in a 256-thread block; R3 had NO
// redundancy, and the real drag is the 800k device-scope stat atomics onto
// 1KB (all XCDs serializing at one coherence point).  This version scatters
// stat atomics over 32 replicated buffers (blockIdx&31) -> contention /32.
__global__ __launch_bounds__(256, 6) void k_fused(
    const unsigned int* __restrict__ xb, const unsigned int* __restrict__ rb,
    const int* __restrict__ offsets, const unsigned int* __restrict__ packed,
    const unsigned short* __restrict__ WT, unsigned short* __restrict__ C,
    float* __restrict__ statsRep, int M) {
  __shared__ unsigned short As[32][392];
  __shared__ float sSum[128], sSq[128];
  const int tid = threadIdx.x;
  const int m0 = blockIdx.x * 32;
  const int wave = tid >> 6, lane = tid & 63;
  const int quad = lane >> 4, l16 = lane & 15;
  const int qid = (wave << 2) | quad;          // 0..15
  if (tid < 128) { sSum[tid] = 0.f; sSq[tid] = 0.f; }

  // ---- aggregation phase: each quad-group owns 6 consecutive keys ----
#pragma unroll 1
  for (int i = 0; i < 6; ++i) {
    int kloc = qid * 6 + i;                  // 0..95
    int dloc = kloc / 3, cls = kloc - dloc * 3;
    float a0[8] = {}, a1[8] = {};
    int dst = m0 + dloc;
    if (dst < M) {
      int key = dst * 3 + cls;
      int s = offsets[key], e = offsets[key + 1];
      int j = s;
      for (; j + 1 < e; j += 2) {
        unsigned int p0 = packed[j], p1 = packed[j + 1];
        int s0 = p0 & 0xFFFFF, t0 = p0 >> 20;
        int s1 = p1 & 0xFFFFF, t1 = p1 >> 20;
        uint4 h0 = *(const uint4*)&xb[(size_t)s0 * 64 + l16 * 4];
        uint4 r0 = *(const uint4*)&rb[(size_t)t0 * 64 + l16 * 4];
        uint4 h1 = *(const uint4*)&xb[(size_t)s1 * 64 + l16 * 4];
        uint4 r1 = *(const uint4*)&rb[(size_t)t1 * 64 + l16 * 4];
        acc8(a0, h0, r0);
        acc8(a1, h1, r1);
      }
      if (j < e) {
        unsigned int p0 = packed[j];
        int s0 = p0 & 0xFFFFF, t0 = p0 >> 20;
        uint4 h0 = *(const uint4*)&xb[(size_t)s0 * 64 + l16 * 4];
        uint4 r0 = *(const uint4*)&rb[(size_t)t0 * 64 + l16 * 4];
        acc8(a0, h0, r0);
      }
    }
    uint4 o;
    o.x = pack2bf(a0[0] + a1[0], a0[1] + a1[1]);
    o.y = pack2bf(a0[2] + a1[2], a0[3] + a1[3]);
    o.z = pack2bf(a0[4] + a1[4], a0[5] + a1[5]);
    o.w = pack2bf(a0[6] + a1[6], a0[7] + a1[7]);
    *(uint4*)&As[dloc][cls * 128 + l16 * 8] = o;   // zeros for OOB dst
  }
  __syncthreads();

  // ---- GEMM phase: C[32x128] = As[32x384] @ WT^T, B streamed from L2 ----
  const unsigned short* Wp = WT + (size_t)(wave * 32 + l16) * 384 + quad * 8;
  short8 bc0 = *(const short8*)(Wp);
  short8 bc1 = *(const short8*)(Wp + 16 * 384);
  f32x4 acc[2][2] = {};
#pragma unroll 1
  for (int it = 0; it < 12; ++it) {
    short8 bn0, bn1;
    if (it < 11) {
      bn0 = *(const short8*)(Wp + (it + 1) * 32);
      bn1 = *(const short8*)(Wp + 16 * 384 + (it + 1) * 32);
    }
    short8 a[2];
#pragma unroll
    for (int t = 0; t < 2; ++t) a[t] = *(const short8*)&As[t * 16 + l16][it * 32 + quad * 8];
#pragma unroll
    for (int t = 0; t < 2; ++t) {
      acc[t][0] = __builtin_amdgcn_mfma_f32_16x16x32_bf16(a[t], bc0, acc[t][0], 0, 0, 0);
      acc[t][1] = __builtin_amdgcn_mfma_f32_16x16x32_bf16(a[t], bc1, acc[t][1], 0, 0, 0);
    }
    if (it < 11) { bc0 = bn0; bc1 = bn1; }
  }

  // ---- epilogue: bf16 C store + BN stats (replicated atomics) ----
  float ps[2] = {}, pq[2] = {};
#pragma unroll
  for (int t = 0; t < 2; ++t) {
#pragma unroll
    for (int reg = 0; reg < 4; ++reg) {
      int m = m0 + t * 16 + quad * 4 + reg;
      if (m < M) {
#pragma unroll
        for (int ct = 0; ct < 2; ++ct) {
          float v = acc[t][ct][reg];
          int col = wave * 32 + ct * 16 + l16;
          C[(size_t)m * 128 + col] = f2bf(v);
          ps[ct] += v; pq[ct] += v * v;
        }
      }
    }
  }
#pragma unroll
  for (int ct = 0; ct < 2; ++ct) {
    int col = wave * 32 + ct * 16 + l16;
    atomicAdd(&sSum[col], ps[ct]);
    atomicAdd(&sSq[col], pq[ct]);
  }
  __syncthreads();
  if (tid < 128) {
    float* rep = statsRep + ((blockIdx.x & 31) << 8);
    atomicAdd(&rep[tid], sSum[tid]);
    atomicAdd(&rep[128 + tid], sSq[tid]);
  }
}

// fold 32 stat replicas -> final 256 floats (sums|sumsq)
__global__ void k_collapse(const float* __restrict__ rep, float* __restrict__ fin) {
  int c = threadIdx.x;
  float s = 0.f;
#pragma unroll
  for (int r = 0; r < 32; ++r) s += rep[r * 256 + c];
  fin[c] = s;
}

// norm + tanh, uint4-vectorized (4 bf16-pairs per thread)
__global__ void k_norm(const uint4* __restrict__ Cb4,
                       const float* __restrict__ sums, const float* __restrict__ sumsq,
                       const float* __restrict__ gamma, const float* __restrict__ beta,
                       float invN, uint4* __restrict__ xb4, int nQuad) {
  __shared__ float sc_s[128], bi_s[128];
  if (threadIdx.x < 128) {
    int c = threadIdx.x;
    float mean = sums[c] * invN;
    float var = fmaxf(sumsq[c] * invN - mean * mean, 0.f);
    float sc = rsqrtf(var + 1e-5f) * gamma[c];
    sc_s[c] = sc;
    bi_s[c] = beta[c] - mean * sc;
  }
  __syncthreads();
  int i = blockIdx.x * blockDim.x + threadIdx.x;
  if (i >= nQuad) return;
  uint4 v = Cb4[i];
  int j = (i * 4) & 63;   // pair-col of v.x (4|64 -> stays within the row)
  uint4 o;
  float2 f;
  f = bf2f(v.x);
  o.x = pack2bf(tanhf(fmaf(f.x, sc_s[2*j],   bi_s[2*j])),   tanhf(fmaf(f.y, sc_s[2*j+1], bi_s[2*j+1])));
  f = bf2f(v.y);
  o.y = pack2bf(tanhf(fmaf(f.x, sc_s[2*j+2], bi_s[2*j+2])), tanhf(fmaf(f.y, sc_s[2*j+3], bi_s[2*j+3])));
  f = bf2f(v.z);
  o.z = pack2bf(tanhf(fmaf(f.x, sc_s[2*j+4], bi_s[2*j+4])), tanhf(fmaf(f.y, sc_s[2*j+5], bi_s[2*j+5])));
  f = bf2f(v.w);
  o.w = pack2bf(tanhf(fmaf(f.x, sc_s[2*j+6], bi_s[2*j+6])), tanhf(fmaf(f.y, sc_s[2*j+7], bi_s[2*j+7])));
  xb4[i] = o;
}

// one wave per triple: sum_d |x[h]+r[rel]-x[t]|
__global__ void k_score(const unsigned int* __restrict__ xb, const float* __restrict__ r,
                        const int* __restrict__ triples, float* __restrict__ out, int nT) {
  int gid = blockIdx.x * blockDim.x + threadIdx.x;
  int t = gid >> 6;
  if (t >= nT) return;
  int lane = gid & 63;
  int h = triples[t * 3], rel = triples[t * 3 + 1], tl = triples[t * 3 + 2];
  float2 a = bf2f(xb[(size_t)h * 64 + lane]);
  float2 b = *(const float2*)&r[(size_t)rel * 128 + lane * 2];
  float2 cc = bf2f(xb[(size_t)tl * 64 + lane]);
  float s = fabsf(a.x + b.x - cc.x) + fabsf(a.y + b.y - cc.y);
#pragma unroll
  for (int off = 32; off > 0; off >>= 1) s += __shfl_down(s, off);
  if (lane == 0) out[t] = s;
}

extern "C" void kernel_launch(void* const* d_in, const int* in_sizes, int n_in,
                              void* d_out, int out_size, void* d_ws, size_t ws_size,
                              hipStream_t stream) {
  const float* ent   = (const float*)d_in[0];
  const float* bases = (const float*)d_in[1];
  const float* coeff = (const float*)d_in[2];
  const float* selfr = (const float*)d_in[3];
  const float* W1    = (const float*)d_in[4];
  const float* relw1 = (const float*)d_in[5];
  const float* g1    = (const float*)d_in[6];
  const float* b1    = (const float*)d_in[7];
  const float* W2    = (const float*)d_in[8];
  const float* relw2 = (const float*)d_in[9];
  const float* g2    = (const float*)d_in[10];
  const float* b2    = (const float*)d_in[11];
  const int* ent_ids = (const int*)d_in[12];
  const int* ei      = (const int*)d_in[13];
  const int* et      = (const int*)d_in[14];
  const int* yk      = (const int*)d_in[15];
  const int* triples = (const int*)d_in[16];

  const int M  = in_sizes[0] / 128;   // 100000
  const int nE = in_sizes[14];        // 800000
  const int nT = in_sizes[16] / 3;    // 4096
  const int nKeys = M * 3;
  const int nScanBlocks = (nKeys + 1023) / 1024;
  const int rsz = (nKeys + 7) / 8;

  // workspace layout (~88 MB)
  float* p = (float*)d_ws;
  float* r2    = p; p += 401 * 128;
  float* statsAll = p; p += 16896;     // 64 replicas x 256 + 2 finals x 256
  float* rep1 = statsAll;
  float* rep2 = statsAll + 32 * 256;
  float* fin1 = statsAll + 64 * 256;
  float* fin2 = fin1 + 256;
  unsigned short* Cb  = (unsigned short*)p;                       // M*128 bf16
  unsigned int* entbf = (unsigned int*)(Cb + (size_t)M * 128);    // M*64
  unsigned int* xb    = entbf + (size_t)M * 64;                   // M*64
  unsigned int* rfb   = xb + (size_t)M * 64;                      // 401*64
  unsigned int* r1b   = rfb + 401 * 64;                           // 401*64
  unsigned short* WT1 = (unsigned short*)(r1b + 401 * 64);
  unsigned short* WT2 = WT1 + 128 * 384;
  int* counts  = (int*)(WT2 + 128 * 384);
  int* offsets = counts + nKeys;
  int* cursor  = offsets + nKeys + 1;
  int* slocal  = cursor + nKeys;
  int* sblock  = slocal + nKeys;
  int* scarry  = sblock + nScanBlocks;
  unsigned int* bucket = (unsigned int*)(scarry + nScanBlocks);

  float* out = (float*)d_out;

  const int nPairs = M * 64;
  const int nQuad  = M * 16;
  const int cvtB = (nPairs + 255) / 256;
  const int cntB = (nKeys + 255) / 256;
  const int zeroB = 66;                       // 16896 / 256
  const int prepBlocks = 585 + cvtB + cntB + zeroB;
  const int fusedBlocks = (M + 31) / 32;
  const int normBlocks = (nQuad + 255) / 256;
  const dim3 rangedGrid(8, (nE + 1023) / 1024);

  // one prep dispatch: r-chain, weight cvt, entity cvt (+ent_ids fold),
  // counts zero, stat zero
  k_prep<<<prepBlocks, 256, 0, stream>>>(coeff, bases, selfr, relw1, relw2,
                                         rfb, r1b, r2, W1, W2, WT1, WT2,
                                         ent, ent_ids, entbf, counts, statsAll,
                                         nPairs, nKeys, cvtB, cntB);

  // CSR over (dst, class)
  k_histR<<<rangedGrid, 256, 0, stream>>>(ei, yk, counts, nE, rsz);
  k_scan1<<<nScanBlocks, 1024, 0, stream>>>(counts, slocal, sblock, nKeys);
  k_scan2<<<1, 1024, 0, stream>>>(sblock, scarry, offsets, nKeys, nScanBlocks);
  k_scan3<<<nScanBlocks, 1024, 0, stream>>>(slocal, scarry, offsets, cursor, nKeys);
  k_fillR<<<rangedGrid, 256, 0, stream>>>(ei, et, yk, cursor, bucket, nE, rsz);

  // ---- layer 1 (fused agg+GEMM+stats) ----
  k_fused<<<fusedBlocks, 256, 0, stream>>>(entbf, rfb, offsets, bucket, WT1,
                                           Cb, rep1, M);
  k_collapse<<<1, 256, 0, stream>>>(rep1, fin1);
  k_norm<<<normBlocks, 256, 0, stream>>>((const uint4*)Cb, fin1, fin1 + 128, g1, b1,
                                         1.0f / M, (uint4*)xb, nQuad);

  // ---- layer 2 ----
  k_fused<<<fusedBlocks, 256, 0, stream>>>(xb, r1b, offsets, bucket, WT2,
                                           Cb, rep2, M);
  k_collapse<<<1, 256, 0, stream>>>(rep2, fin2);
  k_norm<<<normBlocks, 256, 0, stream>>>((const uint4*)Cb, fin2, fin2 + 128, g2, b2,
                                         1.0f / M, (uint4*)xb, nQuad);

  // ---- scoring ----
  k_score<<<(nT * 64 + 255) / 256, 256, 0, stream>>>(xb, r2, triples, out, nT);
}